// Round 1
// baseline (2316.840 us; speedup 1.0000x reference)
//
#include <hip/hip_runtime.h>
#include <hip/hip_bf16.h>

// Problem constants (from reference):
//   x: (8, 4096, 512) f32  -> NQ = 32768 rows, D = 512
//   codebook: (4096, 512) f32 -> M = 4096
// Outputs (concatenated f32): q_st[NQ*D], commitment[NQ], cbn[M*D]
#define NQ 32768
#define D  512
#define M  4096

// ---------------- Kernel 1: normalize codebook rows -> out cbn segment ----
__global__ void k_norm_cb(const float* __restrict__ cb, float* __restrict__ cbn) {
    int row = blockIdx.x;                       // 4096 blocks, 256 threads
    const float2* src = (const float2*)(cb + (size_t)row * D);
    float2 v = src[threadIdx.x];                // 256 * 2 = 512 elements
    float ss = v.x * v.x + v.y * v.y;
    #pragma unroll
    for (int o = 32; o > 0; o >>= 1) ss += __shfl_down(ss, o, 64);
    __shared__ float partial[4];
    __shared__ float scale_s;
    if ((threadIdx.x & 63) == 0) partial[threadIdx.x >> 6] = ss;
    __syncthreads();
    if (threadIdx.x == 0) {
        float t = partial[0] + partial[1] + partial[2] + partial[3];
        scale_s = 1.0f / fmaxf(sqrtf(t), 1e-12f);
    }
    __syncthreads();
    float sc = scale_s;
    float2 o2; o2.x = v.x * sc; o2.y = v.y * sc;
    ((float2*)(cbn + (size_t)row * D))[threadIdx.x] = o2;
}

// ---------------- Kernel 2: 1/max(||x_row||, eps) per query row ------------
__global__ void k_xnorm(const float* __restrict__ x, float* __restrict__ invn) {
    int wave = threadIdx.x >> 6, lane = threadIdx.x & 63;
    int row = blockIdx.x * 4 + wave;            // 8192 blocks * 4 rows
    const float4* src = (const float4*)(x + (size_t)row * D);
    float4 a = src[lane];                       // fully coalesced
    float4 b = src[lane + 64];
    float ss = a.x*a.x + a.y*a.y + a.z*a.z + a.w*a.w
             + b.x*b.x + b.y*b.y + b.z*b.z + b.w*b.w;
    #pragma unroll
    for (int o = 32; o > 0; o >>= 1) ss += __shfl_down(ss, o, 64);
    if (lane == 0) invn[row] = 1.0f / fmaxf(sqrtf(ss), 1e-12f);
}

// ---------------- Kernel 3: fused f32 GEMM + streaming argmax --------------
// Block: 256 threads = 16x16; tile 64 queries x 64 codes, 4x4 per thread.
// Grid: 512 blocks (exactly 2 per CU). Each block sweeps all M codes so the
// argmax stays block-local.
#define BN 64
#define BM 64
#define BK 16
#define LSTR 68   // stride 68 floats = 272 B = 16B-aligned; banks: <=2-way (free)

__launch_bounds__(256, 2)
__global__ void k_argmax(const float* __restrict__ x, const float* __restrict__ cbn,
                         float* __restrict__ maxdot, int* __restrict__ idxout) {
    __shared__ __align__(16) float xs[BK * LSTR];
    __shared__ __align__(16) float cs[BK * LSTR];

    int tid = threadIdx.x;
    int tx = tid & 15, ty = tid >> 4;
    int qbase = blockIdx.x * BN;

    // staging coords: thread loads one float4 along K, scatters 4 scalars (transpose)
    int sq    = tid >> 2;          // 0..63  (row within tile)
    int skseg = (tid & 3) * 4;     // 0,4,8,12 (k offset)
    const float* xg  = x   + ((size_t)(qbase + sq)) * D + skseg;
    const float* cg0 = cbn + ((size_t)sq) * D + skseg;

    float best[4]; int bidx[4];
    #pragma unroll
    for (int i = 0; i < 4; i++) { best[i] = -1e30f; bidx[i] = 0; }

    for (int mt = 0; mt < M / BM; mt++) {
        float s[4][4] = {};
        const float* cg = cg0 + (size_t)mt * BM * D;
        float4 ax = *(const float4*)(xg);
        float4 ac = *(const float4*)(cg);
        for (int kt = 0; kt < D / BK; kt++) {
            __syncthreads();   // protect LDS from previous iteration's readers
            xs[(skseg + 0) * LSTR + sq] = ax.x;
            xs[(skseg + 1) * LSTR + sq] = ax.y;
            xs[(skseg + 2) * LSTR + sq] = ax.z;
            xs[(skseg + 3) * LSTR + sq] = ax.w;
            cs[(skseg + 0) * LSTR + sq] = ac.x;
            cs[(skseg + 1) * LSTR + sq] = ac.y;
            cs[(skseg + 2) * LSTR + sq] = ac.z;
            cs[(skseg + 3) * LSTR + sq] = ac.w;
            if (kt + 1 < D / BK) {     // register prefetch of next K-slab
                ax = *(const float4*)(xg + (kt + 1) * BK);
                ac = *(const float4*)(cg + (kt + 1) * BK);
            }
            __syncthreads();
            #pragma unroll
            for (int k = 0; k < BK; k++) {
                float4 a = *(const float4*)&xs[k * LSTR + ty * 4];
                float4 b = *(const float4*)&cs[k * LSTR + tx * 4];
                s[0][0] = fmaf(a.x, b.x, s[0][0]);
                s[0][1] = fmaf(a.x, b.y, s[0][1]);
                s[0][2] = fmaf(a.x, b.z, s[0][2]);
                s[0][3] = fmaf(a.x, b.w, s[0][3]);
                s[1][0] = fmaf(a.y, b.x, s[1][0]);
                s[1][1] = fmaf(a.y, b.y, s[1][1]);
                s[1][2] = fmaf(a.y, b.z, s[1][2]);
                s[1][3] = fmaf(a.y, b.w, s[1][3]);
                s[2][0] = fmaf(a.z, b.x, s[2][0]);
                s[2][1] = fmaf(a.z, b.y, s[2][1]);
                s[2][2] = fmaf(a.z, b.z, s[2][2]);
                s[2][3] = fmaf(a.z, b.w, s[2][3]);
                s[3][0] = fmaf(a.w, b.x, s[3][0]);
                s[3][1] = fmaf(a.w, b.y, s[3][1]);
                s[3][2] = fmaf(a.w, b.z, s[3][2]);
                s[3][3] = fmaf(a.w, b.w, s[3][3]);
            }
        }
        // streaming top-1; strict '>' + ascending index order == np.argmax ties
        #pragma unroll
        for (int i = 0; i < 4; i++) {
            #pragma unroll
            for (int j = 0; j < 4; j++) {
                int ci = mt * BM + tx * 4 + j;
                if (s[i][j] > best[i]) { best[i] = s[i][j]; bidx[i] = ci; }
            }
        }
    }

    // cross-thread merge: 16 candidates per query row, in reused LDS
    __syncthreads();
    float* rv = xs;            // 64*16 floats fits in 16*68
    int*   ri = (int*)cs;
    #pragma unroll
    for (int i = 0; i < 4; i++) {
        rv[(ty * 4 + i) * 16 + tx] = best[i];
        ri[(ty * 4 + i) * 16 + tx] = bidx[i];
    }
    __syncthreads();
    if (tid < BN) {
        float bv = rv[tid * 16]; int bi = ri[tid * 16];
        for (int t = 1; t < 16; t++) {
            float v = rv[tid * 16 + t]; int id = ri[tid * 16 + t];
            if (v > bv || (v == bv && id < bi)) { bv = v; bi = id; }
        }
        maxdot[qbase + tid] = bv;
        idxout[qbase + tid] = bi;
    }
}

// ---------------- Kernel 4: gather q_st rows + commitment ------------------
__global__ void k_write(const float* __restrict__ cbn, const int* __restrict__ idx,
                        const float* __restrict__ maxdot, const float* __restrict__ invn,
                        float* __restrict__ outq, float* __restrict__ outc) {
    int wave = threadIdx.x >> 6, lane = threadIdx.x & 63;
    int row = blockIdx.x * 4 + wave;
    int id = idx[row];
    const float4* src = (const float4*)(cbn + (size_t)id * D);
    float4* dst = (float4*)(outq + (size_t)row * D);
    dst[lane]      = src[lane];
    dst[lane + 64] = src[lane + 64];
    if (lane == 0) outc[row] = 1.0f - maxdot[row] * invn[row];
}

extern "C" void kernel_launch(void* const* d_in, const int* in_sizes, int n_in,
                              void* d_out, int out_size, void* d_ws, size_t ws_size,
                              hipStream_t stream) {
    const float* x  = (const float*)d_in[0];
    const float* cb = (const float*)d_in[1];
    float* out  = (float*)d_out;
    float* outq = out;                    // NQ*D
    float* outc = out + (size_t)NQ * D;   // NQ
    float* cbn  = outc + NQ;              // M*D (reference's 3rd output)

    float* invn   = (float*)d_ws;         // NQ f32
    float* maxdot = invn + NQ;            // NQ f32
    int*   idx    = (int*)(maxdot + NQ);  // NQ i32

    k_norm_cb<<<M, 256, 0, stream>>>(cb, cbn);
    k_xnorm<<<NQ / 4, 256, 0, stream>>>(x, invn);
    k_argmax<<<NQ / BN, 256, 0, stream>>>(x, cbn, maxdot, idx);
    k_write<<<NQ / 4, 256, 0, stream>>>(cbn, idx, maxdot, invn, outq, outc);
}

// Round 2
// 744.781 us; speedup vs baseline: 3.1108x; 3.1108x over previous
//
#include <hip/hip_runtime.h>
#include <hip/hip_bf16.h>
#include <stdint.h>

// Problem: x (8,4096,512) f32 -> NQ=32768 rows; codebook (4096,512) f32.
// Outputs f32 concat: q_st[NQ*D], commitment[NQ], cbn[M*D]
#define NQ 32768
#define D  512
#define M  4096
#define TAU 1e-5f

typedef __bf16 bf16x8 __attribute__((ext_vector_type(8)));
typedef float  f32x4  __attribute__((ext_vector_type(4)));

// ---------------- helpers ----------------
__device__ __forceinline__ unsigned short f2bf(float f) {
    unsigned u = __float_as_uint(f);
    u += 0x7fff + ((u >> 16) & 1);          // RNE
    return (unsigned short)(u >> 16);
}
__device__ __forceinline__ float bf2f(unsigned short h) {
    return __uint_as_float(((unsigned)h) << 16);
}
__device__ __forceinline__ void gl2lds16(const void* g, void* l) {
    __builtin_amdgcn_global_load_lds(
        (const __attribute__((address_space(1))) unsigned int*)g,
        (__attribute__((address_space(3))) unsigned int*)l,
        16, 0, 0);
}

// ---------------- Kernel: normalize codebook rows -> cbn (f32 output) -----
__global__ void k_norm_cb(const float* __restrict__ cb, float* __restrict__ cbn) {
    int row = blockIdx.x;
    const float2* src = (const float2*)(cb + (size_t)row * D);
    float2 v = src[threadIdx.x];
    float ss = v.x * v.x + v.y * v.y;
    #pragma unroll
    for (int o = 32; o > 0; o >>= 1) ss += __shfl_down(ss, o, 64);
    __shared__ float partial[4];
    __shared__ float scale_s;
    if ((threadIdx.x & 63) == 0) partial[threadIdx.x >> 6] = ss;
    __syncthreads();
    if (threadIdx.x == 0) {
        float t = partial[0] + partial[1] + partial[2] + partial[3];
        scale_s = 1.0f / fmaxf(sqrtf(t), 1e-12f);
    }
    __syncthreads();
    float sc = scale_s;
    float2 o2; o2.x = v.x * sc; o2.y = v.y * sc;
    ((float2*)(cbn + (size_t)row * D))[threadIdx.x] = o2;
}

// ---------------- Kernel: retile cbn into MFMA-slab bf16 hi/lo ------------
// Tiled layout: 16B chunk index = ((ct*4+kc)*16 + t)*64 + m
//   ct: code-tile of 64, kc: k-chunk of 128, t: k-octet in chunk, m: code in tile
__global__ void k_tile_cb(const float* __restrict__ cbn,
                          unsigned short* __restrict__ chi_t,
                          unsigned short* __restrict__ clo_t) {
    int ct = blockIdx.x >> 2, kc = blockIdx.x & 3;
    __shared__ float xs[64 * 129];
    int tid = threadIdx.x;
    #pragma unroll
    for (int pass = 0; pass < 8; pass++) {
        int row = pass * 8 + (tid >> 5);
        int col = (tid & 31) * 4;
        float4 v = *(const float4*)(cbn + (size_t)(ct * 64 + row) * D + kc * 128 + col);
        xs[row * 129 + col + 0] = v.x;
        xs[row * 129 + col + 1] = v.y;
        xs[row * 129 + col + 2] = v.z;
        xs[row * 129 + col + 3] = v.w;
    }
    __syncthreads();
    #pragma unroll
    for (int i = 0; i < 4; i++) {
        int cid = i * 256 + tid;
        int t = cid >> 6, m = cid & 63;
        unsigned short h[8], l[8];
        #pragma unroll
        for (int j = 0; j < 8; j++) {
            float v = xs[m * 129 + t * 8 + j];
            h[j] = f2bf(v);
            l[j] = f2bf(v - bf2f(h[j]));
        }
        size_t chunk = ((size_t)blockIdx.x * 16 + t) * 64 + m;   // 16B units
        int4 hv, lv;
        hv.x = h[0] | (h[1] << 16); hv.y = h[2] | (h[3] << 16);
        hv.z = h[4] | (h[5] << 16); hv.w = h[6] | (h[7] << 16);
        lv.x = l[0] | (l[1] << 16); lv.y = l[2] | (l[3] << 16);
        lv.z = l[4] | (l[5] << 16); lv.w = l[6] | (l[7] << 16);
        *(int4*)(chi_t + chunk * 8) = hv;
        *(int4*)(clo_t + chunk * 8) = lv;
    }
}

// ---------------- Kernel: x row norms + normalized bf16 hi/lo -------------
__global__ void k_prep_x(const float* __restrict__ x, float* __restrict__ invn,
                         unsigned short* __restrict__ xh, unsigned short* __restrict__ xl) {
    int wv = threadIdx.x >> 6, lane = threadIdx.x & 63;
    int row = blockIdx.x * 4 + wv;
    const float4* src = (const float4*)(x + (size_t)row * D);
    float4 a = src[lane];
    float4 b = src[lane + 64];
    float ss = a.x*a.x + a.y*a.y + a.z*a.z + a.w*a.w
             + b.x*b.x + b.y*b.y + b.z*b.z + b.w*b.w;
    #pragma unroll
    for (int o = 32; o > 0; o >>= 1) ss += __shfl_xor(ss, o, 64);
    float iv = 1.0f / fmaxf(sqrtf(ss), 1e-12f);
    if (lane == 0) invn[row] = iv;
    float va[4] = {a.x*iv, a.y*iv, a.z*iv, a.w*iv};
    float vb[4] = {b.x*iv, b.y*iv, b.z*iv, b.w*iv};
    unsigned short ha[4], la[4], hb[4], lb[4];
    #pragma unroll
    for (int j = 0; j < 4; j++) {
        ha[j] = f2bf(va[j]); la[j] = f2bf(va[j] - bf2f(ha[j]));
        hb[j] = f2bf(vb[j]); lb[j] = f2bf(vb[j] - bf2f(hb[j]));
    }
    uint2 u;
    u.x = ha[0] | (ha[1] << 16); u.y = ha[2] | (ha[3] << 16);
    *(uint2*)(xh + (size_t)row * D + lane * 4) = u;
    u.x = hb[0] | (hb[1] << 16); u.y = hb[2] | (hb[3] << 16);
    *(uint2*)(xh + (size_t)row * D + 256 + lane * 4) = u;
    u.x = la[0] | (la[1] << 16); u.y = la[2] | (la[3] << 16);
    *(uint2*)(xl + (size_t)row * D + lane * 4) = u;
    u.x = lb[0] | (lb[1] << 16); u.y = lb[2] | (lb[3] << 16);
    *(uint2*)(xl + (size_t)row * D + 256 + lane * 4) = u;
}

// ---------------- Kernel: MFMA 3-term screen + top-2 ----------------------
__device__ __forceinline__ void stage_slab(const unsigned short* chi_t,
                                           const unsigned short* clo_t,
                                           int step, bf16x8* bufh, bf16x8* bufl,
                                           int w, int lane) {
    const char* sh = (const char*)chi_t + (size_t)step * 16384;
    const char* sl = (const char*)clo_t + (size_t)step * 16384;
    #pragma unroll
    for (int i = 0; i < 4; i++) {
        int s = w * 4 + i;                       // 0..31, wave-uniform
        if (s < 16)
            gl2lds16(sh + (size_t)s * 1024 + lane * 16, (void*)(bufh + s * 64));
        else
            gl2lds16(sl + (size_t)(s - 16) * 1024 + lane * 16, (void*)(bufl + (s - 16) * 64));
    }
}

__launch_bounds__(512, 2)
__global__ void k_screen(const unsigned short* __restrict__ xh_g,
                         const unsigned short* __restrict__ xl_g,
                         const unsigned short* __restrict__ chi_t,
                         const unsigned short* __restrict__ clo_t,
                         float* __restrict__ bestv, float* __restrict__ marg,
                         int* __restrict__ bidx_g) {
    __shared__ bf16x8 lbuf[2][2][1024];          // [buf][hi/lo][slice*64+m] = 64 KB
    int tid = threadIdx.x;
    int lane = tid & 63, w = tid >> 6;
    int l15 = lane & 15, quad = lane >> 4;
    int q = blockIdx.x * 128 + w * 16 + l15;

    // pin x fragments (full K) in registers: B-operand layout [n=lane&15][k=quad*8+j]
    bf16x8 xh[16], xl[16];
    {
        const unsigned short* xr = xh_g + (size_t)q * D;
        const unsigned short* xr2 = xl_g + (size_t)q * D;
        #pragma unroll
        for (int kg = 0; kg < 16; kg++) {
            xh[kg] = *(const bf16x8*)(xr + kg * 32 + quad * 8);
            xl[kg] = *(const bf16x8*)(xr2 + kg * 32 + quad * 8);
        }
    }

    f32x4 acc[4];
    #pragma unroll
    for (int cb = 0; cb < 4; cb++) acc[cb] = (f32x4){0.f, 0.f, 0.f, 0.f};
    float best = -1e30f, second = -1e30f;
    int bi = 0;

    stage_slab(chi_t, clo_t, 0, &lbuf[0][0][0], &lbuf[0][1][0], w, lane);

    for (int ct = 0; ct < 64; ct++) {
        #pragma unroll
        for (int kc = 0; kc < 4; kc++) {
            __syncthreads();                     // staged buf[kc&1] ready; prev readers done
            int step = ct * 4 + kc;
            if (step + 1 < 256)
                stage_slab(chi_t, clo_t, step + 1,
                           &lbuf[(kc + 1) & 1][0][0], &lbuf[(kc + 1) & 1][1][0], w, lane);
            #pragma unroll
            for (int ks = 0; ks < 4; ks++) {
                int cbase = (ks * 4 + quad) * 64 + l15;
                #pragma unroll
                for (int cb = 0; cb < 4; cb++) {
                    bf16x8 ah = lbuf[kc & 1][0][cbase + cb * 16];
                    bf16x8 al = lbuf[kc & 1][1][cbase + cb * 16];
                    acc[cb] = __builtin_amdgcn_mfma_f32_16x16x32_bf16(ah, xh[kc * 4 + ks], acc[cb], 0, 0, 0);
                    acc[cb] = __builtin_amdgcn_mfma_f32_16x16x32_bf16(ah, xl[kc * 4 + ks], acc[cb], 0, 0, 0);
                    acc[cb] = __builtin_amdgcn_mfma_f32_16x16x32_bf16(al, xh[kc * 4 + ks], acc[cb], 0, 0, 0);
                }
            }
        }
        // top-2 update; per-lane code indices ascend with (ct, cb, r)
        #pragma unroll
        for (int cb = 0; cb < 4; cb++) {
            #pragma unroll
            for (int r = 0; r < 4; r++) {
                float v = acc[cb][r];
                int ci = ct * 64 + cb * 16 + quad * 4 + r;
                bool better = v > best;
                second = better ? best : fmaxf(second, v);
                bi = better ? ci : bi;
                best = better ? v : best;
            }
            acc[cb] = (f32x4){0.f, 0.f, 0.f, 0.f};
        }
    }

    // merge the 4 quads holding the same query (xor 16, 32)
    #pragma unroll
    for (int mm = 16; mm <= 32; mm <<= 1) {
        float ob = __shfl_xor(best, mm, 64);
        float os = __shfl_xor(second, mm, 64);
        int   oi = __shfl_xor(bi, mm, 64);
        bool take = (ob > best) || (ob == best && oi < bi);
        float lo = take ? best : ob;
        best = take ? ob : best;
        bi   = take ? oi : bi;
        second = fmaxf(lo, fmaxf(second, os));
    }
    if (quad == 0) {
        bestv[q]  = best;
        marg[q]   = best - second;
        bidx_g[q] = bi;
    }
}

// ---------------- Kernel: exact f32 rescan for tiny-margin queries --------
__global__ void k_rescan(const float* __restrict__ x, const float* __restrict__ invn,
                         const float* __restrict__ cbn, const float* __restrict__ marg,
                         float* __restrict__ maxdot, int* __restrict__ idxout) {
    int qq = blockIdx.x;
    if (marg[qq] >= TAU) return;
    __shared__ float xs[D];
    __shared__ float rv[256];
    __shared__ int   ri[256];
    int tid = threadIdx.x;
    float iv = invn[qq];
    xs[tid]       = x[(size_t)qq * D + tid] * iv;
    xs[tid + 256] = x[(size_t)qq * D + 256 + tid] * iv;
    __syncthreads();
    float best = -1e30f; int bi = 0;
    for (int c0 = 0; c0 < M; c0 += 256) {
        int c = c0 + tid;
        const float4* rp = (const float4*)(cbn + (size_t)c * D);
        float dot = 0.f;
        #pragma unroll 8
        for (int k = 0; k < D / 4; k++) {
            float4 r = rp[k];
            float4 xv = *(const float4*)&xs[k * 4];
            dot = fmaf(xv.x, r.x, dot);
            dot = fmaf(xv.y, r.y, dot);
            dot = fmaf(xv.z, r.z, dot);
            dot = fmaf(xv.w, r.w, dot);
        }
        if (dot > best) { best = dot; bi = c; }   // c ascending per thread
    }
    rv[tid] = best; ri[tid] = bi;
    __syncthreads();
    for (int s = 128; s > 0; s >>= 1) {
        if (tid < s) {
            float o = rv[tid + s]; int oi = ri[tid + s];
            if (o > rv[tid] || (o == rv[tid] && oi < ri[tid])) { rv[tid] = o; ri[tid] = oi; }
        }
        __syncthreads();
    }
    if (tid == 0) { maxdot[qq] = rv[0]; idxout[qq] = ri[0]; }
}

// ---------------- Kernel: gather q_st + commitment (cosine in maxdot) -----
__global__ void k_write_new(const float* __restrict__ cbn, const int* __restrict__ idx,
                            const float* __restrict__ maxdot,
                            float* __restrict__ outq, float* __restrict__ outc) {
    int wave = threadIdx.x >> 6, lane = threadIdx.x & 63;
    int row = blockIdx.x * 4 + wave;
    int id = idx[row];
    const float4* src = (const float4*)(cbn + (size_t)id * D);
    float4* dst = (float4*)(outq + (size_t)row * D);
    dst[lane]      = src[lane];
    dst[lane + 64] = src[lane + 64];
    if (lane == 0) outc[row] = 1.0f - maxdot[row];
}

// ================= fallback path (round-1 f32 VALU) ======================
__global__ void k_xnorm(const float* __restrict__ x, float* __restrict__ invn) {
    int wave = threadIdx.x >> 6, lane = threadIdx.x & 63;
    int row = blockIdx.x * 4 + wave;
    const float4* src = (const float4*)(x + (size_t)row * D);
    float4 a = src[lane];
    float4 b = src[lane + 64];
    float ss = a.x*a.x + a.y*a.y + a.z*a.z + a.w*a.w
             + b.x*b.x + b.y*b.y + b.z*b.z + b.w*b.w;
    #pragma unroll
    for (int o = 32; o > 0; o >>= 1) ss += __shfl_down(ss, o, 64);
    if (lane == 0) invn[row] = 1.0f / fmaxf(sqrtf(ss), 1e-12f);
}

#define BN 64
#define BM 64
#define BK 16
#define LSTR 68

__launch_bounds__(256, 2)
__global__ void k_argmax(const float* __restrict__ x, const float* __restrict__ cbn,
                         float* __restrict__ maxdot, int* __restrict__ idxout) {
    __shared__ __align__(16) float xs[BK * LSTR];
    __shared__ __align__(16) float cs[BK * LSTR];
    int tid = threadIdx.x;
    int tx = tid & 15, ty = tid >> 4;
    int qbase = blockIdx.x * BN;
    int sq = tid >> 2;
    int skseg = (tid & 3) * 4;
    const float* xg  = x   + ((size_t)(qbase + sq)) * D + skseg;
    const float* cg0 = cbn + ((size_t)sq) * D + skseg;
    float best[4]; int bidx[4];
    #pragma unroll
    for (int i = 0; i < 4; i++) { best[i] = -1e30f; bidx[i] = 0; }
    for (int mt = 0; mt < M / BM; mt++) {
        float s[4][4] = {};
        const float* cg = cg0 + (size_t)mt * BM * D;
        float4 ax = *(const float4*)(xg);
        float4 ac = *(const float4*)(cg);
        for (int kt = 0; kt < D / BK; kt++) {
            __syncthreads();
            xs[(skseg + 0) * LSTR + sq] = ax.x;
            xs[(skseg + 1) * LSTR + sq] = ax.y;
            xs[(skseg + 2) * LSTR + sq] = ax.z;
            xs[(skseg + 3) * LSTR + sq] = ax.w;
            cs[(skseg + 0) * LSTR + sq] = ac.x;
            cs[(skseg + 1) * LSTR + sq] = ac.y;
            cs[(skseg + 2) * LSTR + sq] = ac.z;
            cs[(skseg + 3) * LSTR + sq] = ac.w;
            if (kt + 1 < D / BK) {
                ax = *(const float4*)(xg + (kt + 1) * BK);
                ac = *(const float4*)(cg + (kt + 1) * BK);
            }
            __syncthreads();
            #pragma unroll
            for (int k = 0; k < BK; k++) {
                float4 a = *(const float4*)&xs[k * LSTR + ty * 4];
                float4 b = *(const float4*)&cs[k * LSTR + tx * 4];
                s[0][0] = fmaf(a.x, b.x, s[0][0]); s[0][1] = fmaf(a.x, b.y, s[0][1]);
                s[0][2] = fmaf(a.x, b.z, s[0][2]); s[0][3] = fmaf(a.x, b.w, s[0][3]);
                s[1][0] = fmaf(a.y, b.x, s[1][0]); s[1][1] = fmaf(a.y, b.y, s[1][1]);
                s[1][2] = fmaf(a.y, b.z, s[1][2]); s[1][3] = fmaf(a.y, b.w, s[1][3]);
                s[2][0] = fmaf(a.z, b.x, s[2][0]); s[2][1] = fmaf(a.z, b.y, s[2][1]);
                s[2][2] = fmaf(a.z, b.z, s[2][2]); s[2][3] = fmaf(a.z, b.w, s[2][3]);
                s[3][0] = fmaf(a.w, b.x, s[3][0]); s[3][1] = fmaf(a.w, b.y, s[3][1]);
                s[3][2] = fmaf(a.w, b.z, s[3][2]); s[3][3] = fmaf(a.w, b.w, s[3][3]);
            }
        }
        #pragma unroll
        for (int i = 0; i < 4; i++) {
            #pragma unroll
            for (int j = 0; j < 4; j++) {
                int ci = mt * BM + tx * 4 + j;
                if (s[i][j] > best[i]) { best[i] = s[i][j]; bidx[i] = ci; }
            }
        }
    }
    __syncthreads();
    float* rv = xs;
    int*   ri = (int*)cs;
    #pragma unroll
    for (int i = 0; i < 4; i++) {
        rv[(ty * 4 + i) * 16 + tx] = best[i];
        ri[(ty * 4 + i) * 16 + tx] = bidx[i];
    }
    __syncthreads();
    if (tid < BN) {
        float bv = rv[tid * 16]; int bb = ri[tid * 16];
        for (int t = 1; t < 16; t++) {
            float v = rv[tid * 16 + t]; int id = ri[tid * 16 + t];
            if (v > bv || (v == bv && id < bb)) { bv = v; bb = id; }
        }
        maxdot[qbase + tid] = bv;
        idxout[qbase + tid] = bb;
    }
}

__global__ void k_write_old(const float* __restrict__ cbn, const int* __restrict__ idx,
                            const float* __restrict__ maxdot, const float* __restrict__ invn,
                            float* __restrict__ outq, float* __restrict__ outc) {
    int wave = threadIdx.x >> 6, lane = threadIdx.x & 63;
    int row = blockIdx.x * 4 + wave;
    int id = idx[row];
    const float4* src = (const float4*)(cbn + (size_t)id * D);
    float4* dst = (float4*)(outq + (size_t)row * D);
    dst[lane]      = src[lane];
    dst[lane + 64] = src[lane + 64];
    if (lane == 0) outc[row] = 1.0f - maxdot[row] * invn[row];
}

// ================= launch =================================================
extern "C" void kernel_launch(void* const* d_in, const int* in_sizes, int n_in,
                              void* d_out, int out_size, void* d_ws, size_t ws_size,
                              hipStream_t stream) {
    const float* x  = (const float*)d_in[0];
    const float* cb = (const float*)d_in[1];
    float* out  = (float*)d_out;
    float* outq = out;
    float* outc = out + (size_t)NQ * D;
    float* cbn  = outc + NQ;

    float* invn   = (float*)d_ws;
    float* maxdot = invn + NQ;
    float* marg   = maxdot + NQ;
    int*   idx    = (int*)(marg + NQ);
    unsigned short* xh    = (unsigned short*)(idx + NQ);
    unsigned short* xl    = xh + (size_t)NQ * D;
    unsigned short* chi_t = xl + (size_t)NQ * D;
    unsigned short* clo_t = chi_t + (size_t)M * D;
    size_t needed = (size_t)(clo_t + (size_t)M * D - (unsigned short*)d_ws) * 2;

    k_norm_cb<<<M, 256, 0, stream>>>(cb, cbn);

    if (ws_size >= needed) {
        k_prep_x<<<NQ / 4, 256, 0, stream>>>(x, invn, xh, xl);
        k_tile_cb<<<256, 256, 0, stream>>>(cbn, chi_t, clo_t);
        k_screen<<<256, 512, 0, stream>>>(xh, xl, chi_t, clo_t, maxdot, marg, idx);
        k_rescan<<<NQ, 256, 0, stream>>>(x, invn, cbn, marg, maxdot, idx);
        k_write_new<<<NQ / 4, 256, 0, stream>>>(cbn, idx, maxdot, outq, outc);
    } else {
        k_xnorm<<<NQ / 4, 256, 0, stream>>>(x, invn);
        k_argmax<<<NQ / BN, 256, 0, stream>>>(x, cbn, maxdot, idx);
        k_write_old<<<NQ / 4, 256, 0, stream>>>(cbn, idx, maxdot, invn, outq, outc);
    }
}

// Round 3
// 513.368 us; speedup vs baseline: 4.5130x; 1.4508x over previous
//
#include <hip/hip_runtime.h>
#include <hip/hip_bf16.h>
#include <stdint.h>

// Problem: x (8,4096,512) f32 -> NQ=32768 rows; codebook (4096,512) f32.
// Outputs f32 concat: q_st[NQ*D], commitment[NQ], cbn[M*D]
#define NQ 32768
#define D  512
#define M  4096
#define TAU 1e-5f

typedef __bf16 bf16x8 __attribute__((ext_vector_type(8)));
typedef float  f32x4  __attribute__((ext_vector_type(4)));

// ---------------- helpers ----------------
__device__ __forceinline__ unsigned short f2bf(float f) {
    unsigned u = __float_as_uint(f);
    u += 0x7fff + ((u >> 16) & 1);          // RNE
    return (unsigned short)(u >> 16);
}
__device__ __forceinline__ float bf2f(unsigned short h) {
    return __uint_as_float(((unsigned)h) << 16);
}
__device__ __forceinline__ void gl2lds16(const void* g, void* l) {
    __builtin_amdgcn_global_load_lds(
        (const __attribute__((address_space(1))) unsigned int*)g,
        (__attribute__((address_space(3))) unsigned int*)l,
        16, 0, 0);
}

// ---------------- Kernel: normalize codebook rows -> cbn (f32 output) -----
__global__ void k_norm_cb(const float* __restrict__ cb, float* __restrict__ cbn) {
    int row = blockIdx.x;
    const float2* src = (const float2*)(cb + (size_t)row * D);
    float2 v = src[threadIdx.x];
    float ss = v.x * v.x + v.y * v.y;
    #pragma unroll
    for (int o = 32; o > 0; o >>= 1) ss += __shfl_down(ss, o, 64);
    __shared__ float partial[4];
    __shared__ float scale_s;
    if ((threadIdx.x & 63) == 0) partial[threadIdx.x >> 6] = ss;
    __syncthreads();
    if (threadIdx.x == 0) {
        float t = partial[0] + partial[1] + partial[2] + partial[3];
        scale_s = 1.0f / fmaxf(sqrtf(t), 1e-12f);
    }
    __syncthreads();
    float sc = scale_s;
    float2 o2; o2.x = v.x * sc; o2.y = v.y * sc;
    ((float2*)(cbn + (size_t)row * D))[threadIdx.x] = o2;
}

// ---------------- Kernel: retile cbn into MFMA-slab bf16 hi/lo ------------
// Tiled layout: 16B chunk index = ((ct*4+kc)*16 + t)*64 + m
__global__ void k_tile_cb(const float* __restrict__ cbn,
                          unsigned short* __restrict__ chi_t,
                          unsigned short* __restrict__ clo_t) {
    int ct = blockIdx.x >> 2, kc = blockIdx.x & 3;
    __shared__ float xs[64 * 129];
    int tid = threadIdx.x;
    #pragma unroll
    for (int pass = 0; pass < 8; pass++) {
        int row = pass * 8 + (tid >> 5);
        int col = (tid & 31) * 4;
        float4 v = *(const float4*)(cbn + (size_t)(ct * 64 + row) * D + kc * 128 + col);
        xs[row * 129 + col + 0] = v.x;
        xs[row * 129 + col + 1] = v.y;
        xs[row * 129 + col + 2] = v.z;
        xs[row * 129 + col + 3] = v.w;
    }
    __syncthreads();
    #pragma unroll
    for (int i = 0; i < 4; i++) {
        int cid = i * 256 + tid;
        int t = cid >> 6, m = cid & 63;
        unsigned short h[8], l[8];
        #pragma unroll
        for (int j = 0; j < 8; j++) {
            float v = xs[m * 129 + t * 8 + j];
            h[j] = f2bf(v);
            l[j] = f2bf(v - bf2f(h[j]));
        }
        size_t chunk = ((size_t)blockIdx.x * 16 + t) * 64 + m;   // 16B units
        int4 hv, lv;
        hv.x = h[0] | (h[1] << 16); hv.y = h[2] | (h[3] << 16);
        hv.z = h[4] | (h[5] << 16); hv.w = h[6] | (h[7] << 16);
        lv.x = l[0] | (l[1] << 16); lv.y = l[2] | (l[3] << 16);
        lv.z = l[4] | (l[5] << 16); lv.w = l[6] | (l[7] << 16);
        *(int4*)(chi_t + chunk * 8) = hv;
        *(int4*)(clo_t + chunk * 8) = lv;
    }
}

// ---------------- Kernel: x row norms + normalized bf16 hi/lo -------------
__global__ void k_prep_x(const float* __restrict__ x, float* __restrict__ invn,
                         unsigned short* __restrict__ xh, unsigned short* __restrict__ xl) {
    int wv = threadIdx.x >> 6, lane = threadIdx.x & 63;
    int row = blockIdx.x * 4 + wv;
    const float4* src = (const float4*)(x + (size_t)row * D);
    float4 a = src[lane];
    float4 b = src[lane + 64];
    float ss = a.x*a.x + a.y*a.y + a.z*a.z + a.w*a.w
             + b.x*b.x + b.y*b.y + b.z*b.z + b.w*b.w;
    #pragma unroll
    for (int o = 32; o > 0; o >>= 1) ss += __shfl_xor(ss, o, 64);
    float iv = 1.0f / fmaxf(sqrtf(ss), 1e-12f);
    if (lane == 0) invn[row] = iv;
    float va[4] = {a.x*iv, a.y*iv, a.z*iv, a.w*iv};
    float vb[4] = {b.x*iv, b.y*iv, b.z*iv, b.w*iv};
    unsigned short ha[4], la[4], hb[4], lb[4];
    #pragma unroll
    for (int j = 0; j < 4; j++) {
        ha[j] = f2bf(va[j]); la[j] = f2bf(va[j] - bf2f(ha[j]));
        hb[j] = f2bf(vb[j]); lb[j] = f2bf(vb[j] - bf2f(hb[j]));
    }
    uint2 u;
    u.x = ha[0] | (ha[1] << 16); u.y = ha[2] | (ha[3] << 16);
    *(uint2*)(xh + (size_t)row * D + lane * 4) = u;
    u.x = hb[0] | (hb[1] << 16); u.y = hb[2] | (hb[3] << 16);
    *(uint2*)(xh + (size_t)row * D + 256 + lane * 4) = u;
    u.x = la[0] | (la[1] << 16); u.y = la[2] | (la[3] << 16);
    *(uint2*)(xl + (size_t)row * D + lane * 4) = u;
    u.x = lb[0] | (lb[1] << 16); u.y = lb[2] | (lb[3] << 16);
    *(uint2*)(xl + (size_t)row * D + 256 + lane * 4) = u;
}

// ---------------- Kernel: MFMA 3-term screen + top-2 (values AND indices) -
__device__ __forceinline__ void stage_slab(const unsigned short* chi_t,
                                           const unsigned short* clo_t,
                                           int step, bf16x8* bufh, bf16x8* bufl,
                                           int w, int lane) {
    const char* sh = (const char*)chi_t + (size_t)step * 16384;
    const char* sl = (const char*)clo_t + (size_t)step * 16384;
    #pragma unroll
    for (int i = 0; i < 4; i++) {
        int s = w * 4 + i;                       // 0..31, wave-uniform
        if (s < 16)
            gl2lds16(sh + (size_t)s * 1024 + lane * 16, (void*)(bufh + s * 64));
        else
            gl2lds16(sl + (size_t)(s - 16) * 1024 + lane * 16, (void*)(bufl + (s - 16) * 64));
    }
}

__launch_bounds__(512, 2)
__global__ void k_screen(const unsigned short* __restrict__ xh_g,
                         const unsigned short* __restrict__ xl_g,
                         const unsigned short* __restrict__ chi_t,
                         const unsigned short* __restrict__ clo_t,
                         float* __restrict__ bestv, float* __restrict__ marg,
                         int* __restrict__ bidx_g, int* __restrict__ bidx2_g) {
    __shared__ bf16x8 lbuf[2][2][1024];          // [buf][hi/lo][slice*64+m] = 64 KB
    int tid = threadIdx.x;
    int lane = tid & 63, w = tid >> 6;
    int l15 = lane & 15, quad = lane >> 4;
    int q = blockIdx.x * 128 + w * 16 + l15;

    // pin x fragments (full K) in registers: B-operand layout [n=lane&15][k=quad*8+j]
    bf16x8 xh[16], xl[16];
    {
        const unsigned short* xr = xh_g + (size_t)q * D;
        const unsigned short* xr2 = xl_g + (size_t)q * D;
        #pragma unroll
        for (int kg = 0; kg < 16; kg++) {
            xh[kg] = *(const bf16x8*)(xr + kg * 32 + quad * 8);
            xl[kg] = *(const bf16x8*)(xr2 + kg * 32 + quad * 8);
        }
    }

    f32x4 acc[4];
    #pragma unroll
    for (int cb = 0; cb < 4; cb++) acc[cb] = (f32x4){0.f, 0.f, 0.f, 0.f};
    float best = -1e30f, second = -1e30f;
    int bi = 0, bi2 = 0;

    stage_slab(chi_t, clo_t, 0, &lbuf[0][0][0], &lbuf[0][1][0], w, lane);

    for (int ct = 0; ct < 64; ct++) {
        #pragma unroll
        for (int kc = 0; kc < 4; kc++) {
            __syncthreads();
            int step = ct * 4 + kc;
            if (step + 1 < 256)
                stage_slab(chi_t, clo_t, step + 1,
                           &lbuf[(kc + 1) & 1][0][0], &lbuf[(kc + 1) & 1][1][0], w, lane);
            #pragma unroll
            for (int ks = 0; ks < 4; ks++) {
                int cbase = (ks * 4 + quad) * 64 + l15;
                #pragma unroll
                for (int cb = 0; cb < 4; cb++) {
                    bf16x8 ah = lbuf[kc & 1][0][cbase + cb * 16];
                    bf16x8 al = lbuf[kc & 1][1][cbase + cb * 16];
                    acc[cb] = __builtin_amdgcn_mfma_f32_16x16x32_bf16(ah, xh[kc * 4 + ks], acc[cb], 0, 0, 0);
                    acc[cb] = __builtin_amdgcn_mfma_f32_16x16x32_bf16(ah, xl[kc * 4 + ks], acc[cb], 0, 0, 0);
                    acc[cb] = __builtin_amdgcn_mfma_f32_16x16x32_bf16(al, xh[kc * 4 + ks], acc[cb], 0, 0, 0);
                }
            }
        }
        // streaming top-2 with indices; per-lane code indices ascend with (ct,cb,r)
        #pragma unroll
        for (int cb = 0; cb < 4; cb++) {
            #pragma unroll
            for (int r = 0; r < 4; r++) {
                float v = acc[cb][r];
                int ci = ct * 64 + cb * 16 + quad * 4 + r;
                bool b1 = v > best;
                bool b2 = v > second;
                float ns = b1 ? best : (b2 ? v : second);
                int  ni2 = b1 ? bi   : (b2 ? ci : bi2);
                best = b1 ? v : best;
                bi   = b1 ? ci : bi;
                second = ns;
                bi2    = ni2;
            }
            acc[cb] = (f32x4){0.f, 0.f, 0.f, 0.f};
        }
    }

    // merge the 4 quads holding the same query (xor 16, 32): top-2 of union
    #pragma unroll
    for (int mm = 16; mm <= 32; mm <<= 1) {
        float ob  = __shfl_xor(best, mm, 64);
        float os  = __shfl_xor(second, mm, 64);
        int   oi  = __shfl_xor(bi, mm, 64);
        int   oi2 = __shfl_xor(bi2, mm, 64);
        bool take = (ob > best) || (ob == best && oi < bi);
        float wv = take ? ob : best;   int wi  = take ? oi : bi;
        float c1 = take ? best : ob;   int c1i = take ? bi : oi;    // loser of top duel
        float c2 = take ? os : second; int c2i = take ? oi2 : bi2;  // winner's own 2nd
        bool t2 = (c2 > c1) || (c2 == c1 && c2i < c1i);
        best = wv; bi = wi;
        second = t2 ? c2 : c1;
        bi2    = t2 ? c2i : c1i;
    }
    if (quad == 0) {
        bestv[q]   = best;
        marg[q]    = best - second;
        bidx_g[q]  = bi;
        bidx2_g[q] = bi2;
    }
}

// ---------------- Kernel: gather + commitment, with top-2 exact fixup -----
__global__ void k_write_fix(const float* __restrict__ x, const float* __restrict__ invn,
                            const float* __restrict__ cbn, const float* __restrict__ marg,
                            const float* __restrict__ bestv,
                            const int* __restrict__ idx1, const int* __restrict__ idx2,
                            float* __restrict__ outq, float* __restrict__ outc) {
    int wave = threadIdx.x >> 6, lane = threadIdx.x & 63;
    int row = blockIdx.x * 4 + wave;

    float mdot;
    int id;
    if (marg[row] < TAU) {
        // exact f32 rescore of the two screened candidates (wave-cooperative)
        int i1 = idx1[row], i2 = idx2[row];
        float iv = invn[row];
        const float4* xr = (const float4*)(x + (size_t)row * D);
        const float4* c1 = (const float4*)(cbn + (size_t)i1 * D);
        const float4* c2 = (const float4*)(cbn + (size_t)i2 * D);
        float4 xa = xr[lane], xb = xr[lane + 64];
        float4 p = c1[lane], q4 = c1[lane + 64];
        float d1 = xa.x*p.x + xa.y*p.y + xa.z*p.z + xa.w*p.w
                 + xb.x*q4.x + xb.y*q4.y + xb.z*q4.z + xb.w*q4.w;
        p = c2[lane]; q4 = c2[lane + 64];
        float d2 = xa.x*p.x + xa.y*p.y + xa.z*p.z + xa.w*p.w
                 + xb.x*q4.x + xb.y*q4.y + xb.z*q4.z + xb.w*q4.w;
        #pragma unroll
        for (int o = 32; o > 0; o >>= 1) {
            d1 += __shfl_xor(d1, o, 64);
            d2 += __shfl_xor(d2, o, 64);
        }
        bool take2 = (d2 > d1) || (d2 == d1 && i2 < i1);
        id   = take2 ? i2 : i1;
        mdot = (take2 ? d2 : d1) * iv;
    } else {
        id   = idx1[row];
        mdot = bestv[row];
    }

    const float4* src = (const float4*)(cbn + (size_t)id * D);
    float4* dst = (float4*)(outq + (size_t)row * D);
    dst[lane]      = src[lane];
    dst[lane + 64] = src[lane + 64];
    if (lane == 0) outc[row] = 1.0f - mdot;
}

// ================= fallback path (round-1 f32 VALU) ======================
__global__ void k_xnorm(const float* __restrict__ x, float* __restrict__ invn) {
    int wave = threadIdx.x >> 6, lane = threadIdx.x & 63;
    int row = blockIdx.x * 4 + wave;
    const float4* src = (const float4*)(x + (size_t)row * D);
    float4 a = src[lane];
    float4 b = src[lane + 64];
    float ss = a.x*a.x + a.y*a.y + a.z*a.z + a.w*a.w
             + b.x*b.x + b.y*b.y + b.z*b.z + b.w*b.w;
    #pragma unroll
    for (int o = 32; o > 0; o >>= 1) ss += __shfl_down(ss, o, 64);
    if (lane == 0) invn[row] = 1.0f / fmaxf(sqrtf(ss), 1e-12f);
}

#define BN 64
#define BM 64
#define BK 16
#define LSTR 68

__launch_bounds__(256, 2)
__global__ void k_argmax(const float* __restrict__ x, const float* __restrict__ cbn,
                         float* __restrict__ maxdot, int* __restrict__ idxout) {
    __shared__ __align__(16) float xs[BK * LSTR];
    __shared__ __align__(16) float cs[BK * LSTR];
    int tid = threadIdx.x;
    int tx = tid & 15, ty = tid >> 4;
    int qbase = blockIdx.x * BN;
    int sq = tid >> 2;
    int skseg = (tid & 3) * 4;
    const float* xg  = x   + ((size_t)(qbase + sq)) * D + skseg;
    const float* cg0 = cbn + ((size_t)sq) * D + skseg;
    float best[4]; int bidx[4];
    #pragma unroll
    for (int i = 0; i < 4; i++) { best[i] = -1e30f; bidx[i] = 0; }
    for (int mt = 0; mt < M / BM; mt++) {
        float s[4][4] = {};
        const float* cg = cg0 + (size_t)mt * BM * D;
        float4 ax = *(const float4*)(xg);
        float4 ac = *(const float4*)(cg);
        for (int kt = 0; kt < D / BK; kt++) {
            __syncthreads();
            xs[(skseg + 0) * LSTR + sq] = ax.x;
            xs[(skseg + 1) * LSTR + sq] = ax.y;
            xs[(skseg + 2) * LSTR + sq] = ax.z;
            xs[(skseg + 3) * LSTR + sq] = ax.w;
            cs[(skseg + 0) * LSTR + sq] = ac.x;
            cs[(skseg + 1) * LSTR + sq] = ac.y;
            cs[(skseg + 2) * LSTR + sq] = ac.z;
            cs[(skseg + 3) * LSTR + sq] = ac.w;
            if (kt + 1 < D / BK) {
                ax = *(const float4*)(xg + (kt + 1) * BK);
                ac = *(const float4*)(cg + (kt + 1) * BK);
            }
            __syncthreads();
            #pragma unroll
            for (int k = 0; k < BK; k++) {
                float4 a = *(const float4*)&xs[k * LSTR + ty * 4];
                float4 b = *(const float4*)&cs[k * LSTR + tx * 4];
                s[0][0] = fmaf(a.x, b.x, s[0][0]); s[0][1] = fmaf(a.x, b.y, s[0][1]);
                s[0][2] = fmaf(a.x, b.z, s[0][2]); s[0][3] = fmaf(a.x, b.w, s[0][3]);
                s[1][0] = fmaf(a.y, b.x, s[1][0]); s[1][1] = fmaf(a.y, b.y, s[1][1]);
                s[1][2] = fmaf(a.y, b.z, s[1][2]); s[1][3] = fmaf(a.y, b.w, s[1][3]);
                s[2][0] = fmaf(a.z, b.x, s[2][0]); s[2][1] = fmaf(a.z, b.y, s[2][1]);
                s[2][2] = fmaf(a.z, b.z, s[2][2]); s[2][3] = fmaf(a.z, b.w, s[2][3]);
                s[3][0] = fmaf(a.w, b.x, s[3][0]); s[3][1] = fmaf(a.w, b.y, s[3][1]);
                s[3][2] = fmaf(a.w, b.z, s[3][2]); s[3][3] = fmaf(a.w, b.w, s[3][3]);
            }
        }
        #pragma unroll
        for (int i = 0; i < 4; i++) {
            #pragma unroll
            for (int j = 0; j < 4; j++) {
                int ci = mt * BM + tx * 4 + j;
                if (s[i][j] > best[i]) { best[i] = s[i][j]; bidx[i] = ci; }
            }
        }
    }
    __syncthreads();
    float* rv = xs;
    int*   ri = (int*)cs;
    #pragma unroll
    for (int i = 0; i < 4; i++) {
        rv[(ty * 4 + i) * 16 + tx] = best[i];
        ri[(ty * 4 + i) * 16 + tx] = bidx[i];
    }
    __syncthreads();
    if (tid < BN) {
        float bv = rv[tid * 16]; int bb = ri[tid * 16];
        for (int t = 1; t < 16; t++) {
            float v = rv[tid * 16 + t]; int id = ri[tid * 16 + t];
            if (v > bv || (v == bv && id < bb)) { bv = v; bb = id; }
        }
        maxdot[qbase + tid] = bv;
        idxout[qbase + tid] = bb;
    }
}

__global__ void k_write_old(const float* __restrict__ cbn, const int* __restrict__ idx,
                            const float* __restrict__ maxdot, const float* __restrict__ invn,
                            float* __restrict__ outq, float* __restrict__ outc) {
    int wave = threadIdx.x >> 6, lane = threadIdx.x & 63;
    int row = blockIdx.x * 4 + wave;
    int id = idx[row];
    const float4* src = (const float4*)(cbn + (size_t)id * D);
    float4* dst = (float4*)(outq + (size_t)row * D);
    dst[lane]      = src[lane];
    dst[lane + 64] = src[lane + 64];
    if (lane == 0) outc[row] = 1.0f - maxdot[row] * invn[row];
}

// ================= launch =================================================
extern "C" void kernel_launch(void* const* d_in, const int* in_sizes, int n_in,
                              void* d_out, int out_size, void* d_ws, size_t ws_size,
                              hipStream_t stream) {
    const float* x  = (const float*)d_in[0];
    const float* cb = (const float*)d_in[1];
    float* out  = (float*)d_out;
    float* outq = out;
    float* outc = out + (size_t)NQ * D;
    float* cbn  = outc + NQ;

    float* invn   = (float*)d_ws;
    float* maxdot = invn + NQ;
    float* marg   = maxdot + NQ;
    int*   idx    = (int*)(marg + NQ);
    int*   idx2   = idx + NQ;
    unsigned short* xh    = (unsigned short*)(idx2 + NQ);
    unsigned short* xl    = xh + (size_t)NQ * D;
    unsigned short* chi_t = xl + (size_t)NQ * D;
    unsigned short* clo_t = chi_t + (size_t)M * D;
    size_t needed = (size_t)((char*)(clo_t + (size_t)M * D) - (char*)d_ws);

    k_norm_cb<<<M, 256, 0, stream>>>(cb, cbn);

    if (ws_size >= needed) {
        k_prep_x<<<NQ / 4, 256, 0, stream>>>(x, invn, xh, xl);
        k_tile_cb<<<256, 256, 0, stream>>>(cbn, chi_t, clo_t);
        k_screen<<<256, 512, 0, stream>>>(xh, xl, chi_t, clo_t, maxdot, marg, idx, idx2);
        k_write_fix<<<NQ / 4, 256, 0, stream>>>(x, invn, cbn, marg, maxdot, idx, idx2, outq, outc);
    } else {
        k_xnorm<<<NQ / 4, 256, 0, stream>>>(x, invn);
        k_argmax<<<NQ / BN, 256, 0, stream>>>(x, cbn, maxdot, idx);
        k_write_old<<<NQ / 4, 256, 0, stream>>>(cbn, idx, maxdot, invn, outq, outc);
    }
}